// Round 1
// baseline (337.204 us; speedup 1.0000x reference)
//
#include <hip/hip_runtime.h>
#include <cstdint>
#include <cstddef>

#define S_LEN 2048
#define NHEAD 16
#define HDIM  64
#define HID_  1024

typedef short s8v  __attribute__((ext_vector_type(8)));
typedef short s4v  __attribute__((ext_vector_type(4)));
typedef float f4v  __attribute__((ext_vector_type(4)));

__device__ __forceinline__ short f2b(float x) {
    union { float f; unsigned u; } a; a.f = x;
    unsigned r = a.u + 0x7fffu + ((a.u >> 16) & 1u);
    return (short)(r >> 16);
}

__device__ __forceinline__ void gload_lds16(const void* g, void* l) {
    __builtin_amdgcn_global_load_lds(
        (__attribute__((address_space(1))) void*)const_cast<void*>(g),
        (__attribute__((address_space(3))) void*)l, 16, 0, 0);
}

// ---------------- fp32 -> bf16 convert (vectorized) ----------------
__global__ __launch_bounds__(256) void f2b_kernel(const float* __restrict__ in,
                                                  short* __restrict__ out, int n4) {
    int i = blockIdx.x * 256 + threadIdx.x;
    if (i >= n4) return;
    float4 v = reinterpret_cast<const float4*>(in)[i];
    s4v o;
    o[0] = f2b(v.x); o[1] = f2b(v.y); o[2] = f2b(v.z); o[3] = f2b(v.w);
    reinterpret_cast<s4v*>(out)[i] = o;
}

// ---------------- RoPE table: [S][32] of (cos, sin) ----------------
__global__ __launch_bounds__(256) void rope_table_kernel(float2* __restrict__ tab) {
    int idx = blockIdx.x * 256 + threadIdx.x;   // S*32 = 65536
    int s = idx >> 5, j = idx & 31;
    // inv_freq = 65536^(-2j/64) = 2^(-j/2)
    float inv = exp2f(-0.5f * (float)j);
    float ang = (float)s * inv;
    float2 cs; cs.x = cosf(ang); cs.y = sinf(ang);
    tab[idx] = cs;
}

// ---------------- NT bf16 GEMM: C[m][n] = sum_k A[m][k]*W[n][k] + bias ---------
// mode 0/1: Q/K proj -> +bias, RoPE, bf16 out to [bh][s][d]
// mode 2:   V proj   -> +bias,        bf16 out to [bh][s][d]
// mode 3:   O proj   -> +bias,        fp32 out row-major [m][n] (d_out)
__global__ __launch_bounds__(256) void gemm_nt(
    const short* __restrict__ A, const short* __restrict__ Bw,
    const float* __restrict__ bias,
    short* __restrict__ outb, float* __restrict__ outf,
    const float2* __restrict__ rtab,
    int M, int N, int K, int mode)
{
    __shared__ short Asl[128 * 32];
    __shared__ short Bsl[128 * 32];
    const int t = threadIdx.x;
    const int lane = t & 63;
    const int l15 = lane & 15, l4 = lane >> 4;
    const int wid = t >> 6;
    const int tm = blockIdx.x * 128, tn = blockIdx.y * 128;
    const int wrow = (wid >> 1) * 64, wcol = (wid & 1) * 64;

    f4v acc[4][4];
#pragma unroll
    for (int i = 0; i < 4; ++i)
#pragma unroll
        for (int j = 0; j < 4; ++j) acc[i][j] = (f4v){0.f, 0.f, 0.f, 0.f};

    const int r0 = t >> 2;            // staging row within 64-row half
    const int c0 = (t & 3) * 8;       // k-col (8 bf16 = 16B)
    const int wbase = (t & ~63) * 8;  // wave-uniform LDS slot (shorts)
    const int nK = K >> 5;

    for (int kt = 0; kt < nK; ++kt) {
        const int k0 = kt << 5;
        __syncthreads();
        gload_lds16(A  + (size_t)(tm + r0)      * K + k0 + c0, Asl + wbase);
        gload_lds16(A  + (size_t)(tm + 64 + r0) * K + k0 + c0, Asl + 2048 + wbase);
        gload_lds16(Bw + (size_t)(tn + r0)      * K + k0 + c0, Bsl + wbase);
        gload_lds16(Bw + (size_t)(tn + 64 + r0) * K + k0 + c0, Bsl + 2048 + wbase);
        __syncthreads();
        s8v af[4], bf[4];
#pragma unroll
        for (int i = 0; i < 4; ++i) {
            af[i] = *(const s8v*)&Asl[(wrow + i * 16 + l15) * 32 + 8 * l4];
            bf[i] = *(const s8v*)&Bsl[(wcol + i * 16 + l15) * 32 + 8 * l4];
        }
#pragma unroll
        for (int i = 0; i < 4; ++i)
#pragma unroll
            for (int j = 0; j < 4; ++j)
                acc[i][j] = __builtin_amdgcn_mfma_f32_16x16x32_bf16(af[i], bf[j], acc[i][j], 0, 0, 0);
    }

    if (mode == 3) {
#pragma unroll
        for (int i = 0; i < 4; ++i) {
            int rowb = tm + wrow + i * 16 + l4 * 4;
#pragma unroll
            for (int j = 0; j < 4; ++j) {
                int col = tn + wcol + j * 16 + l15;
                float bv = bias[col];
#pragma unroll
                for (int r = 0; r < 4; ++r)
                    outf[(size_t)(rowb + r) * N + col] = acc[i][j][r] + bv;
            }
        }
    } else if (mode == 2) {
#pragma unroll
        for (int i = 0; i < 4; ++i) {
            int rowb = tm + wrow + i * 16 + l4 * 4;
#pragma unroll
            for (int j = 0; j < 4; ++j) {
                int col = tn + wcol + j * 16 + l15;
                float bv = bias[col];
                int h = col >> 6, d = col & 63;
#pragma unroll
                for (int r = 0; r < 4; ++r) {
                    int row = rowb + r;
                    int b_ = row >> 11, s = row & 2047;
                    outb[(((size_t)(b_ * NHEAD + h) * S_LEN + s) << 6) + d] =
                        f2b(acc[i][j][r] + bv);
                }
            }
        }
    } else {  // Q or K: RoPE epilogue. Wave spans exactly one head (64 cols).
        int h = (tn + wcol) >> 6;
#pragma unroll
        for (int i = 0; i < 4; ++i) {
#pragma unroll
            for (int r = 0; r < 4; ++r) {
                int row = tm + wrow + i * 16 + l4 * 4 + r;
                int b_ = row >> 11, s = row & 2047;
                float2 cs0 = rtab[(s << 5) + l15];
                float2 cs1 = rtab[(s << 5) + 16 + l15];
#pragma unroll
                for (int j = 0; j < 4; ++j) {
                    int col = tn + wcol + j * 16 + l15;
                    int d = col & 63;
                    float v  = acc[i][j][r]     + bias[col];
                    float vp = acc[i][j ^ 2][r] + bias[col ^ 32];  // partner d^32
                    float2 cs = (j & 1) ? cs1 : cs0;               // freq idx = d&31
                    float res = (d < 32) ? (v * cs.x - vp * cs.y)
                                         : (v * cs.x + vp * cs.y);
                    outb[(((size_t)(b_ * NHEAD + h) * S_LEN + s) << 6) + d] = f2b(res);
                }
            }
        }
    }
}

// ---------------- flash attention: 64 q-rows/block, 4 waves x 16 rows ----------
__global__ __launch_bounds__(256) void attn_kernel(
    const short* __restrict__ Q, const short* __restrict__ Kp,
    const short* __restrict__ Vp, short* __restrict__ O)
{
    __shared__ short Kl[64][72];      // [key][d], padded: breaks 128B-stride conflict
    __shared__ short Vl[64][72];      // [d][key] (transposed), padded
    __shared__ short Pl[4][16][40];   // per-wave P relayout buffer, padded
    const int t = threadIdx.x, lane = t & 63, wid = t >> 6;
    const int l15 = lane & 15, l4 = lane >> 4;
    const int bh = blockIdx.y;
    const int qbase = blockIdx.x * 64 + wid * 16;
    const size_t bhoff = (size_t)bh * S_LEN * HDIM;
    const short* Qb = Q + bhoff;
    const short* Kb = Kp + bhoff;
    const short* Vb = Vp + bhoff;

    s8v aq[2];
    {
        const int qrow = qbase + l15;
        aq[0] = *(const s8v*)&Qb[(size_t)qrow * HDIM + 8 * l4];
        aq[1] = *(const s8v*)&Qb[(size_t)qrow * HDIM + 32 + 8 * l4];
    }
    f4v oacc[4];
#pragma unroll
    for (int d = 0; d < 4; ++d) oacc[d] = (f4v){0.f, 0.f, 0.f, 0.f};
    float m[4]    = {-1e30f, -1e30f, -1e30f, -1e30f};
    float lsum[4] = {0.f, 0.f, 0.f, 0.f};
    const float scale = 0.125f;  // 1/sqrt(64)

    const int srow = t >> 3;        // staging: key row (0..31 per pass)
    const int sc8 = (t & 7) * 8;    // d-col base

    for (int kc = 0; kc < S_LEN / 64; ++kc) {
        const int kb = kc * 64;
        __syncthreads();
#pragma unroll
        for (int p = 0; p < 2; ++p) {
            int key = p * 32 + srow;
            s8v kv = *(const s8v*)&Kb[(size_t)(kb + key) * HDIM + sc8];
            *(s8v*)&Kl[key][sc8] = kv;
            s8v vv = *(const s8v*)&Vb[(size_t)(kb + key) * HDIM + sc8];
#pragma unroll
            for (int e = 0; e < 8; ++e) Vl[sc8 + e][key] = vv[e];
        }
        __syncthreads();
#pragma unroll
        for (int g = 0; g < 2; ++g) {
            const int ko = g * 32;
            f4v sf0 = (f4v){0.f, 0.f, 0.f, 0.f}, sf1 = sf0;
            sf0 = __builtin_amdgcn_mfma_f32_16x16x32_bf16(aq[0], *(const s8v*)&Kl[ko + l15][8 * l4], sf0, 0, 0, 0);
            sf0 = __builtin_amdgcn_mfma_f32_16x16x32_bf16(aq[1], *(const s8v*)&Kl[ko + l15][32 + 8 * l4], sf0, 0, 0, 0);
            sf1 = __builtin_amdgcn_mfma_f32_16x16x32_bf16(aq[0], *(const s8v*)&Kl[ko + 16 + l15][8 * l4], sf1, 0, 0, 0);
            sf1 = __builtin_amdgcn_mfma_f32_16x16x32_bf16(aq[1], *(const s8v*)&Kl[ko + 16 + l15][32 + 8 * l4], sf1, 0, 0, 0);

            float p0s[4], p1s[4];
#pragma unroll
            for (int r = 0; r < 4; ++r) {
                float v0 = sf0[r] * scale, v1 = sf1[r] * scale;
                float mx = fmaxf(v0, v1);
                mx = fmaxf(mx, __shfl_xor(mx, 1, 64));
                mx = fmaxf(mx, __shfl_xor(mx, 2, 64));
                mx = fmaxf(mx, __shfl_xor(mx, 4, 64));
                mx = fmaxf(mx, __shfl_xor(mx, 8, 64));
                float mn = fmaxf(m[r], mx);
                float fr = __expf(m[r] - mn);
                float p0 = __expf(v0 - mn), p1 = __expf(v1 - mn);
                float rs = p0 + p1;
                rs += __shfl_xor(rs, 1, 64);
                rs += __shfl_xor(rs, 2, 64);
                rs += __shfl_xor(rs, 4, 64);
                rs += __shfl_xor(rs, 8, 64);
                lsum[r] = lsum[r] * fr + rs;
                m[r] = mn;
#pragma unroll
                for (int d = 0; d < 4; ++d) oacc[d][r] = oacc[d][r] * fr;
                p0s[r] = p0; p1s[r] = p1;
            }
            const int prow = l4 * 4;
#pragma unroll
            for (int r = 0; r < 4; ++r) {
                Pl[wid][prow + r][l15]      = f2b(p0s[r]);
                Pl[wid][prow + r][16 + l15] = f2b(p1s[r]);
            }
            asm volatile("s_waitcnt lgkmcnt(0)" ::: "memory");
            s8v pa = *(const s8v*)&Pl[wid][l15][8 * l4];
#pragma unroll
            for (int d = 0; d < 4; ++d) {
                s8v bv2 = *(const s8v*)&Vl[d * 16 + l15][ko + 8 * l4];
                oacc[d] = __builtin_amdgcn_mfma_f32_16x16x32_bf16(pa, bv2, oacc[d], 0, 0, 0);
            }
        }
    }
    const int b_ = bh >> 4, h = bh & 15;
#pragma unroll
    for (int r = 0; r < 4; ++r) {
        float inv = 1.0f / lsum[r];
        int row = qbase + l4 * 4 + r;
        size_t base = ((size_t)(b_ * S_LEN) + row) * HID_ + h * 64;
#pragma unroll
        for (int d = 0; d < 4; ++d)
            O[base + d * 16 + l15] = f2b(oacc[d][r] * inv);
    }
}

// ---------------- launch ----------------
extern "C" void kernel_launch(void* const* d_in, const int* in_sizes, int n_in,
                              void* d_out, int out_size, void* d_ws, size_t ws_size,
                              hipStream_t stream)
{
    const float* X  = (const float*)d_in[0];
    const float* Wq = (const float*)d_in[1];
    const float* bq = (const float*)d_in[2];
    const float* Wk = (const float*)d_in[3];
    const float* bk = (const float*)d_in[4];
    const float* Wv = (const float*)d_in[5];
    const float* bv = (const float*)d_in[6];
    const float* Wo = (const float*)d_in[7];
    const float* bo = (const float*)d_in[8];
    float* out = (float*)d_out;

    char* ws = (char*)d_ws;
    short*  Xb   = (short*) (ws);                      // 8 MB  [4096][1024] bf16
    short*  Wqb  = (short*) (ws + ( 8u << 20));        // 2 MB
    short*  Wkb  = (short*) (ws + (10u << 20));
    short*  Wvb  = (short*) (ws + (12u << 20));
    short*  Wob  = (short*) (ws + (14u << 20));
    float2* rtab = (float2*)(ws + (16u << 20));        // 512 KB [2048][32]
    short*  Qbh  = (short*) (ws + (17u << 20));        // 8 MB  [32][2048][64]
    short*  Kbh  = (short*) (ws + (25u << 20));
    short*  Vbh  = (short*) (ws + (33u << 20));
    short*  Obf  = (short*) (ws + (41u << 20));        // 8 MB  [4096][1024]

    f2b_kernel<<<4096, 256, 0, stream>>>(X,  Xb,  1048576);
    f2b_kernel<<<1024, 256, 0, stream>>>(Wq, Wqb, 262144);
    f2b_kernel<<<1024, 256, 0, stream>>>(Wk, Wkb, 262144);
    f2b_kernel<<<1024, 256, 0, stream>>>(Wv, Wvb, 262144);
    f2b_kernel<<<1024, 256, 0, stream>>>(Wo, Wob, 262144);
    rope_table_kernel<<<256, 256, 0, stream>>>(rtab);

    dim3 gg(32, 8);
    gemm_nt<<<gg, 256, 0, stream>>>(Xb, Wqb, bq, Qbh, nullptr, rtab, 4096, 1024, 1024, 0);
    gemm_nt<<<gg, 256, 0, stream>>>(Xb, Wkb, bk, Kbh, nullptr, rtab, 4096, 1024, 1024, 1);
    gemm_nt<<<gg, 256, 0, stream>>>(Xb, Wvb, bv, Vbh, nullptr, rtab, 4096, 1024, 1024, 2);
    attn_kernel<<<dim3(32, 32), 256, 0, stream>>>(Qbh, Kbh, Vbh, Obf);
    gemm_nt<<<gg, 256, 0, stream>>>(Obf, Wob, bo, nullptr, out, rtab, 4096, 1024, 1024, 3);
}

// Round 2
// 193.416 us; speedup vs baseline: 1.7434x; 1.7434x over previous
//
#include <hip/hip_runtime.h>
#include <cstdint>
#include <cstddef>

#define S_LEN 2048
#define NHEAD 16
#define HDIM  64
#define HID_  1024

typedef short s8v  __attribute__((ext_vector_type(8)));
typedef short s4v  __attribute__((ext_vector_type(4)));
typedef float f4v  __attribute__((ext_vector_type(4)));
typedef float f16v __attribute__((ext_vector_type(16)));

__device__ __forceinline__ short f2b(float x) {
    union { float f; unsigned u; } a; a.f = x;
    unsigned r = a.u + 0x7fffu + ((a.u >> 16) & 1u);
    return (short)(r >> 16);
}

__device__ __forceinline__ void gload_lds16(const void* g, void* l) {
    __builtin_amdgcn_global_load_lds(
        (__attribute__((address_space(1))) void*)const_cast<void*>(g),
        (__attribute__((address_space(3))) void*)l, 16, 0, 0);
}

__device__ __forceinline__ unsigned cvtpk(float a, float b) {
    unsigned r;
    asm("v_cvt_pk_bf16_f32 %0, %1, %2" : "=v"(r) : "v"(a), "v"(b));
    return r;
}
__device__ __forceinline__ void plswap(unsigned& a, unsigned& b) {
    asm("v_permlane32_swap_b32 %0, %1" : "+v"(a), "+v"(b));
}

// ---------------- fp32 -> bf16 convert (vectorized) ----------------
__global__ __launch_bounds__(256) void f2b_kernel(const float* __restrict__ in,
                                                  short* __restrict__ out, int n4) {
    int i = blockIdx.x * 256 + threadIdx.x;
    if (i >= n4) return;
    float4 v = reinterpret_cast<const float4*>(in)[i];
    s4v o;
    o[0] = f2b(v.x); o[1] = f2b(v.y); o[2] = f2b(v.z); o[3] = f2b(v.w);
    reinterpret_cast<s4v*>(out)[i] = o;
}

// ---------------- RoPE table: [S][32] of (cos, sin) ----------------
__global__ __launch_bounds__(256) void rope_table_kernel(float2* __restrict__ tab) {
    int idx = blockIdx.x * 256 + threadIdx.x;   // S*32 = 65536
    int s = idx >> 5, j = idx & 31;
    float inv = exp2f(-0.5f * (float)j);        // 65536^(-2j/64) = 2^(-j/2)
    float ang = (float)s * inv;
    float2 cs; cs.x = cosf(ang); cs.y = sinf(ang);
    tab[idx] = cs;
}

// ---------------- NT bf16 GEMM: C[m][n] = sum_k A[m][k]*W[n][k] + bias ---------
// mode 0: Q proj -> +bias, RoPE, *0.125*log2e, bf16 -> [bh][s][d]
// mode 1: K proj -> +bias, RoPE,               bf16 -> [bh][s][d]
// mode 2: V proj -> +bias,                     bf16 -> [bh][d][s]  (TRANSPOSED)
// mode 3: O proj -> +bias,                     fp32 row-major (d_out)
__global__ __launch_bounds__(256) void gemm_nt(
    const short* __restrict__ A, const short* __restrict__ Bw,
    const float* __restrict__ bias,
    short* __restrict__ outb, float* __restrict__ outf,
    const float2* __restrict__ rtab,
    int M, int N, int K, int mode)
{
    __shared__ short Asl[128 * 32];
    __shared__ short Bsl[128 * 32];
    const int t = threadIdx.x;
    const int lane = t & 63;
    const int l15 = lane & 15, l4 = lane >> 4;
    const int wid = t >> 6;
    const int tm = blockIdx.x * 128, tn = blockIdx.y * 128;
    const int wrow = (wid >> 1) * 64, wcol = (wid & 1) * 64;

    f4v acc[4][4];
#pragma unroll
    for (int i = 0; i < 4; ++i)
#pragma unroll
        for (int j = 0; j < 4; ++j) acc[i][j] = (f4v){0.f, 0.f, 0.f, 0.f};

    const int r0 = t >> 2;
    const int c0 = (t & 3) * 8;
    const int wbase = (t & ~63) * 8;
    const int nK = K >> 5;

    for (int kt = 0; kt < nK; ++kt) {
        const int k0 = kt << 5;
        __syncthreads();
        gload_lds16(A  + (size_t)(tm + r0)      * K + k0 + c0, Asl + wbase);
        gload_lds16(A  + (size_t)(tm + 64 + r0) * K + k0 + c0, Asl + 2048 + wbase);
        gload_lds16(Bw + (size_t)(tn + r0)      * K + k0 + c0, Bsl + wbase);
        gload_lds16(Bw + (size_t)(tn + 64 + r0) * K + k0 + c0, Bsl + 2048 + wbase);
        __syncthreads();
        s8v af[4], bf[4];
#pragma unroll
        for (int i = 0; i < 4; ++i) {
            af[i] = *(const s8v*)&Asl[(wrow + i * 16 + l15) * 32 + 8 * l4];
            bf[i] = *(const s8v*)&Bsl[(wcol + i * 16 + l15) * 32 + 8 * l4];
        }
#pragma unroll
        for (int i = 0; i < 4; ++i)
#pragma unroll
            for (int j = 0; j < 4; ++j)
                acc[i][j] = __builtin_amdgcn_mfma_f32_16x16x32_bf16(af[i], bf[j], acc[i][j], 0, 0, 0);
    }

    if (mode == 3) {
#pragma unroll
        for (int i = 0; i < 4; ++i) {
            int rowb = tm + wrow + i * 16 + l4 * 4;
#pragma unroll
            for (int j = 0; j < 4; ++j) {
                int col = tn + wcol + j * 16 + l15;
                float bv = bias[col];
#pragma unroll
                for (int r = 0; r < 4; ++r)
                    outf[(size_t)(rowb + r) * N + col] = acc[i][j][r] + bv;
            }
        }
    } else if (mode == 2) {   // V: write transposed [bh][d][s]
#pragma unroll
        for (int i = 0; i < 4; ++i) {
            int rowb = tm + wrow + i * 16 + l4 * 4;
            int b_ = rowb >> 11, s0 = rowb & 2047;   // 4-row group never crosses b
#pragma unroll
            for (int j = 0; j < 4; ++j) {
                int col = tn + wcol + j * 16 + l15;
                float bv = bias[col];
                int h = col >> 6, d = col & 63;
                s4v o4;
#pragma unroll
                for (int r = 0; r < 4; ++r) o4[r] = f2b(acc[i][j][r] + bv);
                *(s4v*)&outb[((size_t)((b_ * NHEAD + h) * 64 + d)) * S_LEN + s0] = o4;
            }
        }
    } else {  // Q or K: RoPE epilogue. Wave spans exactly one head (64 cols).
        int h = (tn + wcol) >> 6;
        const float osc = (mode == 0) ? 0.180336880111f : 1.0f;  // 1/8 * log2(e)
#pragma unroll
        for (int i = 0; i < 4; ++i) {
#pragma unroll
            for (int r = 0; r < 4; ++r) {
                int row = tm + wrow + i * 16 + l4 * 4 + r;
                int b_ = row >> 11, s = row & 2047;
                float2 cs0 = rtab[(s << 5) + l15];
                float2 cs1 = rtab[(s << 5) + 16 + l15];
#pragma unroll
                for (int j = 0; j < 4; ++j) {
                    int col = tn + wcol + j * 16 + l15;
                    int d = col & 63;
                    float v  = acc[i][j][r]     + bias[col];
                    float vp = acc[i][j ^ 2][r] + bias[col ^ 32];
                    float2 cs = (j & 1) ? cs1 : cs0;
                    float res = (d < 32) ? (v * cs.x - vp * cs.y)
                                         : (v * cs.x + vp * cs.y);
                    outb[(((size_t)(b_ * NHEAD + h) * S_LEN + s) << 6) + d] = f2b(res * osc);
                }
            }
        }
    }
}

// ---------------- attention: 8 warps x 32 q-rows, swapped-operand 32x32 MFMA ---
// Q pre-scaled by 0.125*log2e in GEMM epilogue; K [bh][s][64]; Vt [bh][d][s].
#define SWB(row, bofs) ((bofs) ^ (((row) & 7) << 4))

__global__ __launch_bounds__(512) void attn2_kernel(
    const short* __restrict__ Q, const short* __restrict__ K,
    const short* __restrict__ Vt, short* __restrict__ O)
{
    __shared__ short Kl[2][4096];   // [key][d] 64x64, XOR-swizzled rows (8KB/buf)
    __shared__ short Vl[2][4096];   // [d][key] 64x64, XOR-swizzled rows

    const int t = threadIdx.x, lane = t & 63, wid = t >> 6;
    const int q5 = lane & 31, hi = lane >> 5;

    // XCD swizzle: each XCD gets 4 bh x all 8 q-blocks -> K/V L2-resident
    const int fid = blockIdx.x + 8 * blockIdx.y;   // 0..255
    const int xcd = fid & 7, loc = fid >> 3;
    const int bh = xcd * 4 + (loc >> 3), qb = loc & 7;

    const short* Qb = Q + (size_t)bh * S_LEN * 64;
    const char*  Kb = (const char*)(K  + (size_t)bh * S_LEN * 64);
    const char*  Vb = (const char*)(Vt + (size_t)bh * S_LEN * 64);
    const int qrow = qb * 256 + wid * 32 + q5;

    // Q B-frags: lane holds Q[q=l&31][d = sl*16 + hi*8 + e]
    s8v qf[4];
#pragma unroll
    for (int sl = 0; sl < 4; ++sl)
        qf[sl] = *(const s8v*)&Qb[(size_t)qrow * 64 + sl * 16 + hi * 8];

    f16v oacc[2];
#pragma unroll
    for (int dt = 0; dt < 2; ++dt)
#pragma unroll
        for (int e = 0; e < 16; ++e) oacc[dt][e] = 0.f;
    float m2 = -1e30f, lsum = 0.f;

    // staging: thread t loads 16B: row = t>>3, colByte = (t&7)*16, swizzled src
    const int skey  = t >> 3;
    const int sboff = (t & 7) * 16;
    const int ssw   = SWB(skey, sboff);
    const size_t koffB = (size_t)skey * 128  + ssw;   // K row stride 128B
    const size_t voffB = (size_t)skey * 4096 + ssw;   // Vt row stride 4096B

#define STAGE(buf, kb) do {                                              \
        gload_lds16(Kb + (size_t)(kb) * 128 + koffB, &Kl[buf][wid * 512]); \
        gload_lds16(Vb + (size_t)(kb) * 2   + voffB, &Vl[buf][wid * 512]); \
    } while (0)

    STAGE(0, 0);
    __syncthreads();

    int cur = 0;
    for (int kt = 0; kt < S_LEN / 64; ++kt) {
        if (kt < S_LEN / 64 - 1) STAGE(cur ^ 1, (kt + 1) * 64);

        // ---- QK^T (swapped): S[key][q], lane q=l&31, 2 chunks of 32 keys ----
        f16v sc[2];
#pragma unroll
        for (int c = 0; c < 2; ++c) {
#pragma unroll
            for (int e = 0; e < 16; ++e) sc[c][e] = 0.f;
            const int krow = c * 32 + q5;
            const char* kbase = (const char*)&Kl[cur][0] + krow * 128;
            __builtin_amdgcn_s_setprio(1);
#pragma unroll
            for (int sl = 0; sl < 4; ++sl) {
                s8v kf = *(const s8v*)(kbase + SWB(krow, sl * 32 + hi * 16));
                sc[c] = __builtin_amdgcn_mfma_f32_32x32x16_bf16(kf, qf[sl], sc[c], 0, 0, 0);
            }
            __builtin_amdgcn_s_setprio(0);
        }

        // ---- online softmax (log2 domain; Q pre-scaled) ----
        float pm = sc[0][0];
#pragma unroll
        for (int e = 1; e < 16; ++e) pm = fmaxf(pm, sc[0][e]);
#pragma unroll
        for (int e = 0; e < 16; ++e) pm = fmaxf(pm, sc[1][e]);
        pm = fmaxf(pm, __shfl_xor(pm, 32, 64));
        if (__any(pm > m2 + 8.0f)) {          // defer-max (T13)
            float m2n = fmaxf(m2, pm);
            float fr = exp2f(m2 - m2n);
            lsum *= fr;
#pragma unroll
            for (int dt = 0; dt < 2; ++dt)
#pragma unroll
                for (int e = 0; e < 16; ++e) oacc[dt][e] *= fr;
            m2 = m2n;
        }
        float ps = 0.f;
#pragma unroll
        for (int c = 0; c < 2; ++c)
#pragma unroll
            for (int e = 0; e < 16; ++e) {
                float p = exp2f(sc[c][e] - m2);
                sc[c][e] = p;
                ps += p;
            }
        lsum += ps;

        // ---- P->bf16 frags (cvt_pk + permlane32_swap) and PV (swapped) ----
#pragma unroll
        for (int c = 0; c < 2; ++c) {
#pragma unroll
            for (int ks = 0; ks < 2; ++ks) {
                const int b0 = ks * 8;
                unsigned x0 = cvtpk(sc[c][b0 + 0], sc[c][b0 + 1]);
                unsigned y0 = cvtpk(sc[c][b0 + 4], sc[c][b0 + 5]);
                unsigned x1 = cvtpk(sc[c][b0 + 2], sc[c][b0 + 3]);
                unsigned y1 = cvtpk(sc[c][b0 + 6], sc[c][b0 + 7]);
                plswap(x0, y0);
                plswap(x1, y1);
                union { unsigned u[4]; s8v s; } pf;
                pf.u[0] = x0; pf.u[1] = x1; pf.u[2] = y0; pf.u[3] = y1;
                __builtin_amdgcn_s_setprio(1);
#pragma unroll
                for (int dt = 0; dt < 2; ++dt) {
                    const int vrow = dt * 32 + q5;
                    s8v vf = *(const s8v*)((const char*)&Vl[cur][0] + vrow * 128 +
                                           SWB(vrow, c * 64 + ks * 32 + hi * 16));
                    oacc[dt] = __builtin_amdgcn_mfma_f32_32x32x16_bf16(vf, pf.s, oacc[dt], 0, 0, 0);
                }
                __builtin_amdgcn_s_setprio(0);
            }
        }

        __syncthreads();   // drains vmcnt (staged loads) + lgkm, flips buffer
        cur ^= 1;
    }

    // ---- epilogue: O^T regs -> O [b][s][h*64+d] ----
    float ls = lsum + __shfl_xor(lsum, 32, 64);
    float inv = 1.0f / ls;
    const int b_ = bh >> 4, h = bh & 15;
    const size_t rbase = ((size_t)(b_ * S_LEN + qrow)) * HID_ + h * 64;
#pragma unroll
    for (int dt = 0; dt < 2; ++dt)
#pragma unroll
        for (int g = 0; g < 4; ++g) {
            s4v o4;
#pragma unroll
            for (int j = 0; j < 4; ++j) o4[j] = f2b(oacc[dt][g * 4 + j] * inv);
            const int d0 = dt * 32 + g * 8 + hi * 4;
            *(s4v*)&O[rbase + d0] = o4;
        }
}

// ---------------- launch ----------------
extern "C" void kernel_launch(void* const* d_in, const int* in_sizes, int n_in,
                              void* d_out, int out_size, void* d_ws, size_t ws_size,
                              hipStream_t stream)
{
    const float* X  = (const float*)d_in[0];
    const float* Wq = (const float*)d_in[1];
    const float* bq = (const float*)d_in[2];
    const float* Wk = (const float*)d_in[3];
    const float* bk = (const float*)d_in[4];
    const float* Wv = (const float*)d_in[5];
    const float* bv = (const float*)d_in[6];
    const float* Wo = (const float*)d_in[7];
    const float* bo = (const float*)d_in[8];
    float* out = (float*)d_out;

    char* ws = (char*)d_ws;
    short*  Xb   = (short*) (ws);                      // 8 MB  [4096][1024] bf16
    short*  Wqb  = (short*) (ws + ( 8u << 20));        // 2 MB
    short*  Wkb  = (short*) (ws + (10u << 20));
    short*  Wvb  = (short*) (ws + (12u << 20));
    short*  Wob  = (short*) (ws + (14u << 20));
    float2* rtab = (float2*)(ws + (16u << 20));        // 512 KB [2048][32]
    short*  Qbh  = (short*) (ws + (17u << 20));        // 8 MB  [32][2048][64]
    short*  Kbh  = (short*) (ws + (25u << 20));
    short*  Vbh  = (short*) (ws + (33u << 20));        // 8 MB  [32][64][2048] (V^T)
    short*  Obf  = (short*) (ws + (41u << 20));        // 8 MB  [4096][1024]

    f2b_kernel<<<4096, 256, 0, stream>>>(X,  Xb,  1048576);
    f2b_kernel<<<1024, 256, 0, stream>>>(Wq, Wqb, 262144);
    f2b_kernel<<<1024, 256, 0, stream>>>(Wk, Wkb, 262144);
    f2b_kernel<<<1024, 256, 0, stream>>>(Wv, Wvb, 262144);
    f2b_kernel<<<1024, 256, 0, stream>>>(Wo, Wob, 262144);
    rope_table_kernel<<<256, 256, 0, stream>>>(rtab);

    dim3 gg(32, 8);
    gemm_nt<<<gg, 256, 0, stream>>>(Xb, Wqb, bq, Qbh, nullptr, rtab, 4096, 1024, 1024, 0);
    gemm_nt<<<gg, 256, 0, stream>>>(Xb, Wkb, bk, Kbh, nullptr, rtab, 4096, 1024, 1024, 1);
    gemm_nt<<<gg, 256, 0, stream>>>(Xb, Wvb, bv, Vbh, nullptr, rtab, 4096, 1024, 1024, 2);
    attn2_kernel<<<dim3(8, 32), 512, 0, stream>>>(Qbh, Kbh, Vbh, Obf);
    gemm_nt<<<gg, 256, 0, stream>>>(Obf, Wob, bo, nullptr, out, rtab, 4096, 1024, 1024, 3);
}

// Round 3
// 160.381 us; speedup vs baseline: 2.1025x; 1.2060x over previous
//
#include <hip/hip_runtime.h>
#include <cstdint>
#include <cstddef>

#define S_LEN 2048
#define NHEAD 16
#define HDIM  64
#define HID_  1024

typedef short s8v  __attribute__((ext_vector_type(8)));
typedef short s4v  __attribute__((ext_vector_type(4)));
typedef float f4v  __attribute__((ext_vector_type(4)));
typedef float f16v __attribute__((ext_vector_type(16)));

__device__ __forceinline__ short f2b(float x) {
    union { float f; unsigned u; } a; a.f = x;
    unsigned r = a.u + 0x7fffu + ((a.u >> 16) & 1u);
    return (short)(r >> 16);
}

__device__ __forceinline__ void gload_lds16(const void* g, void* l) {
    __builtin_amdgcn_global_load_lds(
        (__attribute__((address_space(1))) void*)const_cast<void*>(g),
        (__attribute__((address_space(3))) void*)l, 16, 0, 0);
}

__device__ __forceinline__ unsigned cvtpk(float a, float b) {
    unsigned r;
    asm("v_cvt_pk_bf16_f32 %0, %1, %2" : "=v"(r) : "v"(a), "v"(b));
    return r;
}
__device__ __forceinline__ void plswap(unsigned& a, unsigned& b) {
    asm("v_permlane32_swap_b32 %0, %1" : "+v"(a), "+v"(b));
}

// ---------------- fp32 -> bf16 convert: X ----------------
__global__ __launch_bounds__(256) void f2b_kernel(const float* __restrict__ in,
                                                  short* __restrict__ out, int n4) {
    int i = blockIdx.x * 256 + threadIdx.x;
    if (i >= n4) return;
    float4 v = reinterpret_cast<const float4*>(in)[i];
    s4v o;
    o[0] = f2b(v.x); o[1] = f2b(v.y); o[2] = f2b(v.z); o[3] = f2b(v.w);
    reinterpret_cast<s4v*>(out)[i] = o;
}

// ---------------- fp32 -> bf16 convert: all 4 weight mats in one launch --------
__global__ __launch_bounds__(256) void f2bw_kernel(
    const float* __restrict__ Wq, const float* __restrict__ Wk,
    const float* __restrict__ Wv, const float* __restrict__ Wo,
    short* __restrict__ Wcat, short* __restrict__ Wob)
{
    const int y = blockIdx.y;
    const float* src = (y == 0) ? Wq : (y == 1) ? Wk : (y == 2) ? Wv : Wo;
    short* dst = (y < 3) ? (Wcat + (size_t)y * 1048576) : Wob;
    int i = blockIdx.x * 256 + threadIdx.x;           // 262144 float4 per matrix
    float4 v = reinterpret_cast<const float4*>(src)[i];
    s4v o;
    o[0] = f2b(v.x); o[1] = f2b(v.y); o[2] = f2b(v.z); o[3] = f2b(v.w);
    reinterpret_cast<s4v*>(dst)[i] = o;
}

// ---------------- RoPE table: [S][32] of (cos, sin) ----------------
__global__ __launch_bounds__(256) void rope_table_kernel(float2* __restrict__ tab) {
    int idx = blockIdx.x * 256 + threadIdx.x;   // S*32 = 65536
    int s = idx >> 5, j = idx & 31;
    float inv = exp2f(-0.5f * (float)j);        // 65536^(-2j/64) = 2^(-j/2)
    float ang = (float)s * inv;
    float2 cs; cs.x = cosf(ang); cs.y = sinf(ang);
    tab[idx] = cs;
}

// ---------------- fused QKV GEMM: C[m][n] = X[m][k]*Wcat[n][k] + bias ----------
// n in [0,1024): Q -> +bias, RoPE, *0.125*log2e, bf16 -> Qbh [bh][s][d]
// n in [1024,2048): K -> +bias, RoPE,            bf16 -> Kbh [bh][s][d]
// n in [2048,3072): V -> +bias,                  bf16 -> Vbh [bh][d][s] (transposed)
__global__ __launch_bounds__(256) void gemm_qkv(
    const short* __restrict__ A, const short* __restrict__ Bw,
    const float* __restrict__ bq, const float* __restrict__ bk,
    const float* __restrict__ bv,
    short* __restrict__ Qo, short* __restrict__ Ko, short* __restrict__ Vo,
    const float2* __restrict__ rtab)
{
    __shared__ short Asl[128 * 32];
    __shared__ short Bsl[128 * 32];
    const int t = threadIdx.x;
    const int lane = t & 63;
    const int l15 = lane & 15, l4 = lane >> 4;
    const int wid = t >> 6;
    // XCD-aware decode: 768 blocks; xcd x owns n-tiles [3x, 3x+3)
    const int blk = blockIdx.x;
    const int x = blk & 7, j = blk >> 3;       // j in [0,96)
    const int tn = (x * 3 + j % 3) * 128;
    const int tm = (j / 3) * 128;
    const int K = 1024;
    const int wrow = (wid >> 1) * 64, wcol = (wid & 1) * 64;

    f4v acc[4][4];
#pragma unroll
    for (int i = 0; i < 4; ++i)
#pragma unroll
        for (int jj = 0; jj < 4; ++jj) acc[i][jj] = (f4v){0.f, 0.f, 0.f, 0.f};

    const int r0 = t >> 2;
    const int c0 = (t & 3) * 8;
    const int wbase = (t & ~63) * 8;

    for (int kt = 0; kt < 32; ++kt) {
        const int k0 = kt << 5;
        __syncthreads();
        gload_lds16(A  + (size_t)(tm + r0)      * K + k0 + c0, Asl + wbase);
        gload_lds16(A  + (size_t)(tm + 64 + r0) * K + k0 + c0, Asl + 2048 + wbase);
        gload_lds16(Bw + (size_t)(tn + r0)      * K + k0 + c0, Bsl + wbase);
        gload_lds16(Bw + (size_t)(tn + 64 + r0) * K + k0 + c0, Bsl + 2048 + wbase);
        __syncthreads();
        s8v af[4], bf[4];
#pragma unroll
        for (int i = 0; i < 4; ++i) {
            af[i] = *(const s8v*)&Asl[(wrow + i * 16 + l15) * 32 + 8 * l4];
            bf[i] = *(const s8v*)&Bsl[(wcol + i * 16 + l15) * 32 + 8 * l4];
        }
#pragma unroll
        for (int i = 0; i < 4; ++i)
#pragma unroll
            for (int jj = 0; jj < 4; ++jj)
                acc[i][jj] = __builtin_amdgcn_mfma_f32_16x16x32_bf16(af[i], bf[jj], acc[i][jj], 0, 0, 0);
    }

    const int mode = tn >> 10;                         // 0=Q 1=K 2=V
    const float* bias = (mode == 0) ? bq : (mode == 1) ? bk : bv;
    short* outb = (mode == 0) ? Qo : (mode == 1) ? Ko : Vo;

    if (mode == 2) {   // V: write transposed [bh][d][s]
#pragma unroll
        for (int i = 0; i < 4; ++i) {
            int rowb = tm + wrow + i * 16 + l4 * 4;
            int b_ = rowb >> 11, s0 = rowb & 2047;
#pragma unroll
            for (int jj = 0; jj < 4; ++jj) {
                int col = tn + wcol + jj * 16 + l15;
                int cm = col & 1023;
                float bvv = bias[cm];
                int h = cm >> 6, d = col & 63;
                s4v o4;
#pragma unroll
                for (int r = 0; r < 4; ++r) o4[r] = f2b(acc[i][jj][r] + bvv);
                *(s4v*)&outb[((size_t)((b_ * NHEAD + h) * 64 + d)) * S_LEN + s0] = o4;
            }
        }
    } else {           // Q or K: RoPE. Wave spans exactly one head (64 cols).
        int h = ((tn & 1023) + wcol) >> 6;
        const float osc = (mode == 0) ? 0.180336880111f : 1.0f;  // 1/8 * log2(e)
#pragma unroll
        for (int i = 0; i < 4; ++i) {
#pragma unroll
            for (int r = 0; r < 4; ++r) {
                int row = tm + wrow + i * 16 + l4 * 4 + r;
                int b_ = row >> 11, s = row & 2047;
                float2 cs0 = rtab[(s << 5) + l15];
                float2 cs1 = rtab[(s << 5) + 16 + l15];
#pragma unroll
                for (int jj = 0; jj < 4; ++jj) {
                    int col = tn + wcol + jj * 16 + l15;
                    int cm = col & 1023;
                    int d = col & 63;
                    float v  = acc[i][jj][r]     + bias[cm];
                    float vp = acc[i][jj ^ 2][r] + bias[cm ^ 32];
                    float2 cs = (jj & 1) ? cs1 : cs0;
                    float res = (d < 32) ? (v * cs.x - vp * cs.y)
                                         : (v * cs.x + vp * cs.y);
                    outb[(((size_t)(b_ * NHEAD + h) * S_LEN + s) << 6) + d] = f2b(res * osc);
                }
            }
        }
    }
}

// ---------------- O-proj GEMM: BM=64 x BN=128 (512 blocks) ---------------------
__global__ __launch_bounds__(256) void gemm_o(
    const short* __restrict__ A, const short* __restrict__ Bw,
    const float* __restrict__ bias, float* __restrict__ outf)
{
    __shared__ short Asl[64 * 32];
    __shared__ short Bsl[128 * 32];
    const int t = threadIdx.x;
    const int lane = t & 63;
    const int l15 = lane & 15, l4 = lane >> 4;
    const int wid = t >> 6;
    const int blk = blockIdx.x;                 // 512
    const int tn = (blk & 7) * 128;             // xcd x owns n-tile x
    const int tm = (blk >> 3) * 64;
    const int K = 1024, N = 1024;
    const int wrow = (wid >> 1) * 32, wcol = (wid & 1) * 64;

    f4v acc[2][4];
#pragma unroll
    for (int i = 0; i < 2; ++i)
#pragma unroll
        for (int jj = 0; jj < 4; ++jj) acc[i][jj] = (f4v){0.f, 0.f, 0.f, 0.f};

    const int r0 = t >> 2;
    const int c0 = (t & 3) * 8;
    const int wbase = (t & ~63) * 8;

    for (int kt = 0; kt < 32; ++kt) {
        const int k0 = kt << 5;
        __syncthreads();
        gload_lds16(A  + (size_t)(tm + r0)      * K + k0 + c0, Asl + wbase);
        gload_lds16(Bw + (size_t)(tn + r0)      * K + k0 + c0, Bsl + wbase);
        gload_lds16(Bw + (size_t)(tn + 64 + r0) * K + k0 + c0, Bsl + 2048 + wbase);
        __syncthreads();
        s8v af[2], bf[4];
#pragma unroll
        for (int i = 0; i < 2; ++i)
            af[i] = *(const s8v*)&Asl[(wrow + i * 16 + l15) * 32 + 8 * l4];
#pragma unroll
        for (int jj = 0; jj < 4; ++jj)
            bf[jj] = *(const s8v*)&Bsl[(wcol + jj * 16 + l15) * 32 + 8 * l4];
#pragma unroll
        for (int i = 0; i < 2; ++i)
#pragma unroll
            for (int jj = 0; jj < 4; ++jj)
                acc[i][jj] = __builtin_amdgcn_mfma_f32_16x16x32_bf16(af[i], bf[jj], acc[i][jj], 0, 0, 0);
    }

#pragma unroll
    for (int i = 0; i < 2; ++i) {
        int rowb = tm + wrow + i * 16 + l4 * 4;
#pragma unroll
        for (int jj = 0; jj < 4; ++jj) {
            int col = tn + wcol + jj * 16 + l15;
            float bv = bias[col];
#pragma unroll
            for (int r = 0; r < 4; ++r)
                outf[(size_t)(rowb + r) * N + col] = acc[i][jj][r] + bv;
        }
    }
}

// ---------------- attention: 4 warps x 32 q-rows, swapped-operand 32x32 MFMA ---
// Q pre-scaled by 0.125*log2e; K [bh][s][64]; Vt [bh][d][s]. 512 blocks.
#define SWB(row, bofs) ((bofs) ^ (((row) & 7) << 4))

__global__ __launch_bounds__(256) void attn2_kernel(
    const short* __restrict__ Q, const short* __restrict__ K,
    const short* __restrict__ Vt, short* __restrict__ O)
{
    __shared__ short Kl[2][4096];   // [key][d] 64x64, swizzled (8KB/buf)
    __shared__ short Vl[2][4096];   // [d][key] 64x64, swizzled

    const int t = threadIdx.x, lane = t & 63, wid = t >> 6;
    const int q5 = lane & 31, hi = lane >> 5;

    // XCD decode: 512 blocks; xcd x owns bh [4x,4x+4) over all 16 q-blocks
    const int blk = blockIdx.x;
    const int x = blk & 7, j = blk >> 3;       // j in [0,64)
    const int bh = x * 4 + (j & 3), qb = j >> 2;

    const short* Qb = Q + (size_t)bh * S_LEN * 64;
    const char*  Kb = (const char*)(K  + (size_t)bh * S_LEN * 64);
    const char*  Vb = (const char*)(Vt + (size_t)bh * S_LEN * 64);
    const int qrow = qb * 128 + wid * 32 + q5;

    s8v qf[4];
#pragma unroll
    for (int sl = 0; sl < 4; ++sl)
        qf[sl] = *(const s8v*)&Qb[(size_t)qrow * 64 + sl * 16 + hi * 8];

    f16v oacc[2];
#pragma unroll
    for (int dt = 0; dt < 2; ++dt)
#pragma unroll
        for (int e = 0; e < 16; ++e) oacc[dt][e] = 0.f;
    float m2 = -1e30f, lsum = 0.f;

    // staging: 256 threads x 2 rounds: row = rr*32 + t>>3, colByte (t&7)*16
    const int skey  = t >> 3;                  // 0..31
    const int sboff = (t & 7) * 16;
    const int ssw   = SWB(skey, sboff);        // (row&7) invariant under +32
    const size_t koffB = (size_t)skey * 128  + ssw;
    const size_t voffB = (size_t)skey * 4096 + ssw;

#define STAGE(buf, kb) do {                                                        \
        gload_lds16(Kb + (size_t)(kb) * 128 + koffB,              &Kl[buf][wid * 512]);        \
        gload_lds16(Kb + (size_t)(kb) * 128 + koffB + 32 * 128,   &Kl[buf][2048 + wid * 512]); \
        gload_lds16(Vb + (size_t)(kb) * 2   + voffB,              &Vl[buf][wid * 512]);        \
        gload_lds16(Vb + (size_t)(kb) * 2   + voffB + 32 * 4096,  &Vl[buf][2048 + wid * 512]); \
    } while (0)

    STAGE(0, 0);
    __syncthreads();

    int cur = 0;
    for (int kt = 0; kt < S_LEN / 64; ++kt) {
        if (kt < S_LEN / 64 - 1) STAGE(cur ^ 1, (kt + 1) * 64);

        // ---- QK^T (swapped): lane q = l&31; 2 chunks of 32 keys ----
        f16v sc[2];
#pragma unroll
        for (int c = 0; c < 2; ++c) {
#pragma unroll
            for (int e = 0; e < 16; ++e) sc[c][e] = 0.f;
            const int krow = c * 32 + q5;
            const char* kbase = (const char*)&Kl[cur][0] + krow * 128;
            __builtin_amdgcn_s_setprio(1);
#pragma unroll
            for (int sl = 0; sl < 4; ++sl) {
                s8v kf = *(const s8v*)(kbase + SWB(krow, sl * 32 + hi * 16));
                sc[c] = __builtin_amdgcn_mfma_f32_32x32x16_bf16(kf, qf[sl], sc[c], 0, 0, 0);
            }
            __builtin_amdgcn_s_setprio(0);
        }

        // ---- online softmax (log2 domain) ----
        float pm = -1e30f;
#pragma unroll
        for (int c = 0; c < 2; ++c)
#pragma unroll
            for (int e = 0; e < 16; e += 2)
                pm = fmaxf(pm, fmaxf(sc[c][e], sc[c][e + 1]));   // v_max3
        pm = fmaxf(pm, __shfl_xor(pm, 32, 64));
        if (__any(pm > m2 + 8.0f)) {          // defer-max (T13)
            float m2n = fmaxf(m2, pm);
            float fr = __builtin_amdgcn_exp2f(m2 - m2n);
            lsum *= fr;
#pragma unroll
            for (int dt = 0; dt < 2; ++dt)
#pragma unroll
                for (int e = 0; e < 16; ++e) oacc[dt][e] *= fr;
            m2 = m2n;
        }
        float ps = 0.f;
#pragma unroll
        for (int c = 0; c < 2; ++c)
#pragma unroll
            for (int e = 0; e < 16; ++e) {
                float p = __builtin_amdgcn_exp2f(sc[c][e] - m2);
                sc[c][e] = p;
                ps += p;
            }
        lsum += ps;

        // ---- P->bf16 frags (cvt_pk + permlane32_swap) and PV (swapped) ----
#pragma unroll
        for (int c = 0; c < 2; ++c) {
#pragma unroll
            for (int ks = 0; ks < 2; ++ks) {
                const int b0 = ks * 8;
                unsigned x0 = cvtpk(sc[c][b0 + 0], sc[c][b0 + 1]);
                unsigned y0 = cvtpk(sc[c][b0 + 4], sc[c][b0 + 5]);
                unsigned x1 = cvtpk(sc[c][b0 + 2], sc[c][b0 + 3]);
                unsigned y1 = cvtpk(sc[c][b0 + 6], sc[c][b0 + 7]);
                plswap(x0, y0);
                plswap(x1, y1);
                union { unsigned u[4]; s8v s; } pf;
                pf.u[0] = x0; pf.u[1] = x1; pf.u[2] = y0; pf.u[3] = y1;
                __builtin_amdgcn_s_setprio(1);
#pragma unroll
                for (int dt = 0; dt < 2; ++dt) {
                    const int vrow = dt * 32 + q5;
                    s8v vf = *(const s8v*)((const char*)&Vl[cur][0] + vrow * 128 +
                                           SWB(vrow, c * 64 + ks * 32 + hi * 16));
                    oacc[dt] = __builtin_amdgcn_mfma_f32_32x32x16_bf16(vf, pf.s, oacc[dt], 0, 0, 0);
                }
                __builtin_amdgcn_s_setprio(0);
            }
        }

        __syncthreads();
        cur ^= 1;
    }

    // ---- epilogue ----
    float ls = lsum + __shfl_xor(lsum, 32, 64);
    float inv = 1.0f / ls;
    const int b_ = bh >> 4, h = bh & 15;
    const size_t rbase = ((size_t)(b_ * S_LEN + qrow)) * HID_ + h * 64;
#pragma unroll
    for (int dt = 0; dt < 2; ++dt)
#pragma unroll
        for (int g = 0; g < 4; ++g) {
            s4v o4;
#pragma unroll
            for (int jj = 0; jj < 4; ++jj) o4[jj] = f2b(oacc[dt][g * 4 + jj] * inv);
            const int d0 = dt * 32 + g * 8 + hi * 4;
            *(s4v*)&O[rbase + d0] = o4;
        }
}

// ---------------- launch ----------------
extern "C" void kernel_launch(void* const* d_in, const int* in_sizes, int n_in,
                              void* d_out, int out_size, void* d_ws, size_t ws_size,
                              hipStream_t stream)
{
    const float* X  = (const float*)d_in[0];
    const float* Wq = (const float*)d_in[1];
    const float* bq = (const float*)d_in[2];
    const float* Wk = (const float*)d_in[3];
    const float* bk = (const float*)d_in[4];
    const float* Wv = (const float*)d_in[5];
    const float* bv = (const float*)d_in[6];
    const float* Wo = (const float*)d_in[7];
    const float* bo = (const float*)d_in[8];
    float* out = (float*)d_out;

    char* ws = (char*)d_ws;
    short*  Xb   = (short*) (ws);                      // 8 MB  [4096][1024] bf16
    short*  Wcat = (short*) (ws + ( 8u << 20));        // 6 MB  Wq|Wk|Wv bf16
    short*  Wob  = (short*) (ws + (14u << 20));        // 2 MB
    float2* rtab = (float2*)(ws + (16u << 20));        // 512 KB [2048][32]
    short*  Qbh  = (short*) (ws + (17u << 20));        // 8 MB  [32][2048][64]
    short*  Kbh  = (short*) (ws + (25u << 20));
    short*  Vbh  = (short*) (ws + (33u << 20));        // 8 MB  [32][64][2048] (V^T)
    short*  Obf  = (short*) (ws + (41u << 20));        // 8 MB  [4096][1024]

    f2b_kernel<<<4096, 256, 0, stream>>>(X, Xb, 1048576);
    f2bw_kernel<<<dim3(1024, 4), 256, 0, stream>>>(Wq, Wk, Wv, Wo, Wcat, Wob);
    rope_table_kernel<<<256, 256, 0, stream>>>(rtab);

    gemm_qkv<<<768, 256, 0, stream>>>(Xb, Wcat, bq, bk, bv, Qbh, Kbh, Vbh, rtab);
    attn2_kernel<<<512, 256, 0, stream>>>(Qbh, Kbh, Vbh, Obf);
    gemm_o<<<512, 256, 0, stream>>>(Obf, Wob, bo, out);
}

// Round 4
// 150.983 us; speedup vs baseline: 2.2334x; 1.0622x over previous
//
#include <hip/hip_runtime.h>
#include <cstdint>
#include <cstddef>

#define S_LEN 2048
#define NHEAD 16
#define HDIM  64
#define HID_  1024

typedef short s8v  __attribute__((ext_vector_type(8)));
typedef short s4v  __attribute__((ext_vector_type(4)));
typedef float f4v  __attribute__((ext_vector_type(4)));
typedef float f16v __attribute__((ext_vector_type(16)));

__device__ __forceinline__ short f2b(float x) {
    union { float f; unsigned u; } a; a.f = x;
    unsigned r = a.u + 0x7fffu + ((a.u >> 16) & 1u);
    return (short)(r >> 16);
}

__device__ __forceinline__ void gload_lds16(const void* g, void* l) {
    __builtin_amdgcn_global_load_lds(
        (__attribute__((address_space(1))) void*)const_cast<void*>(g),
        (__attribute__((address_space(3))) void*)l, 16, 0, 0);
}

__device__ __forceinline__ unsigned cvtpk(float a, float b) {
    unsigned r;
    asm("v_cvt_pk_bf16_f32 %0, %1, %2" : "=v"(r) : "v"(a), "v"(b));
    return r;
}
__device__ __forceinline__ void plswap(unsigned& a, unsigned& b) {
    asm("v_permlane32_swap_b32 %0, %1" : "+v"(a), "+v"(b));
}

// ---------------- fp32 -> bf16 convert: X ----------------
__global__ __launch_bounds__(256) void f2b_kernel(const float* __restrict__ in,
                                                  short* __restrict__ out, int n4) {
    int i = blockIdx.x * 256 + threadIdx.x;
    if (i >= n4) return;
    float4 v = reinterpret_cast<const float4*>(in)[i];
    s4v o;
    o[0] = f2b(v.x); o[1] = f2b(v.y); o[2] = f2b(v.z); o[3] = f2b(v.w);
    reinterpret_cast<s4v*>(out)[i] = o;
}

// ---------------- fp32 -> bf16 convert: all 4 weight mats in one launch --------
__global__ __launch_bounds__(256) void f2bw_kernel(
    const float* __restrict__ Wq, const float* __restrict__ Wk,
    const float* __restrict__ Wv, const float* __restrict__ Wo,
    short* __restrict__ Wcat, short* __restrict__ Wob)
{
    const int y = blockIdx.y;
    const float* src = (y == 0) ? Wq : (y == 1) ? Wk : (y == 2) ? Wv : Wo;
    short* dst = (y < 3) ? (Wcat + (size_t)y * 1048576) : Wob;
    int i = blockIdx.x * 256 + threadIdx.x;           // 262144 float4 per matrix
    float4 v = reinterpret_cast<const float4*>(src)[i];
    s4v o;
    o[0] = f2b(v.x); o[1] = f2b(v.y); o[2] = f2b(v.z); o[3] = f2b(v.w);
    reinterpret_cast<s4v*>(dst)[i] = o;
}

// ---------------- RoPE table: [S][32] of (cos, sin) ----------------
__global__ __launch_bounds__(256) void rope_table_kernel(float2* __restrict__ tab) {
    int idx = blockIdx.x * 256 + threadIdx.x;   // S*32 = 65536
    int s = idx >> 5, j = idx & 31;
    float inv = exp2f(-0.5f * (float)j);        // 65536^(-2j/64) = 2^(-j/2)
    float ang = (float)s * inv;
    float2 cs; cs.x = cosf(ang); cs.y = sinf(ang);
    tab[idx] = cs;
}

// ---------------- fused QKV GEMM, 2-phase double-buffered (T3-minimum) ---------
// n in [0,1024): Q -> +bias, RoPE, *0.125*log2e, bf16 -> Qbh [bh][s][d]
// n in [1024,2048): K -> +bias, RoPE,            bf16 -> Kbh [bh][s][d]
// n in [2048,3072): V -> +bias,                  bf16 -> Vbh [bh][d][s] (transposed)
__global__ __launch_bounds__(256) void gemm_qkv(
    const short* __restrict__ A, const short* __restrict__ Bw,
    const float* __restrict__ bq, const float* __restrict__ bk,
    const float* __restrict__ bv,
    short* __restrict__ Qo, short* __restrict__ Ko, short* __restrict__ Vo,
    const float2* __restrict__ rtab)
{
    __shared__ short Asl[2][128 * 32];
    __shared__ short Bsl[2][128 * 32];
    const int t = threadIdx.x;
    const int lane = t & 63;
    const int l15 = lane & 15, l4 = lane >> 4;
    const int wid = t >> 6;
    // XCD-aware decode: 768 blocks; xcd x owns n-tiles [3x, 3x+3)
    const int blk = blockIdx.x;
    const int x = blk & 7, j = blk >> 3;       // j in [0,96)
    const int tn = (x * 3 + j % 3) * 128;
    const int tm = (j / 3) * 128;
    const int K = 1024;
    const int wrow = (wid >> 1) * 64, wcol = (wid & 1) * 64;

    f4v acc[4][4];
#pragma unroll
    for (int i = 0; i < 4; ++i)
#pragma unroll
        for (int jj = 0; jj < 4; ++jj) acc[i][jj] = (f4v){0.f, 0.f, 0.f, 0.f};

    const int r0 = t >> 2;
    const int c0 = (t & 3) * 8;
    const int wbase = (t & ~63) * 8;

#define QSTAGE(buf, kt) do { const int k0_ = (kt) << 5;                            \
        gload_lds16(A  + (size_t)(tm + r0)      * K + k0_ + c0, &Asl[buf][wbase]);        \
        gload_lds16(A  + (size_t)(tm + 64 + r0) * K + k0_ + c0, &Asl[buf][2048 + wbase]); \
        gload_lds16(Bw + (size_t)(tn + r0)      * K + k0_ + c0, &Bsl[buf][wbase]);        \
        gload_lds16(Bw + (size_t)(tn + 64 + r0) * K + k0_ + c0, &Bsl[buf][2048 + wbase]); \
    } while (0)

    QSTAGE(0, 0);
    __syncthreads();                 // drains vmcnt(0): buf0 ready
    int cur = 0;
    for (int kt = 0; kt < 32; ++kt) {
        if (kt < 31) QSTAGE(cur ^ 1, kt + 1);     // issue next-tile loads FIRST
        s8v af[4], bf[4];
#pragma unroll
        for (int i = 0; i < 4; ++i) {
            af[i] = *(const s8v*)&Asl[cur][(wrow + i * 16 + l15) * 32 + 8 * l4];
            bf[i] = *(const s8v*)&Bsl[cur][(wcol + i * 16 + l15) * 32 + 8 * l4];
        }
#pragma unroll
        for (int i = 0; i < 4; ++i)
#pragma unroll
            for (int jj = 0; jj < 4; ++jj)
                acc[i][jj] = __builtin_amdgcn_mfma_f32_16x16x32_bf16(af[i], bf[jj], acc[i][jj], 0, 0, 0);
        __syncthreads();             // one barrier/iter: drains next-tile vmcnt
        cur ^= 1;
    }
#undef QSTAGE

    const int mode = tn >> 10;                         // 0=Q 1=K 2=V
    const float* bias = (mode == 0) ? bq : (mode == 1) ? bk : bv;
    short* outb = (mode == 0) ? Qo : (mode == 1) ? Ko : Vo;

    if (mode == 2) {   // V: write transposed [bh][d][s]
#pragma unroll
        for (int i = 0; i < 4; ++i) {
            int rowb = tm + wrow + i * 16 + l4 * 4;
            int b_ = rowb >> 11, s0 = rowb & 2047;
#pragma unroll
            for (int jj = 0; jj < 4; ++jj) {
                int col = tn + wcol + jj * 16 + l15;
                int cm = col & 1023;
                float bvv = bias[cm];
                int h = cm >> 6, d = col & 63;
                s4v o4;
#pragma unroll
                for (int r = 0; r < 4; ++r) o4[r] = f2b(acc[i][jj][r] + bvv);
                *(s4v*)&outb[((size_t)((b_ * NHEAD + h) * 64 + d)) * S_LEN + s0] = o4;
            }
        }
    } else {           // Q or K: RoPE. Wave spans exactly one head (64 cols).
        int h = ((tn & 1023) + wcol) >> 6;
        const float osc = (mode == 0) ? 0.180336880111f : 1.0f;  // 1/8 * log2(e)
#pragma unroll
        for (int i = 0; i < 4; ++i) {
#pragma unroll
            for (int r = 0; r < 4; ++r) {
                int row = tm + wrow + i * 16 + l4 * 4 + r;
                int b_ = row >> 11, s = row & 2047;
                float2 cs0 = rtab[(s << 5) + l15];
                float2 cs1 = rtab[(s << 5) + 16 + l15];
#pragma unroll
                for (int jj = 0; jj < 4; ++jj) {
                    int col = tn + wcol + jj * 16 + l15;
                    int cm = col & 1023;
                    int d = col & 63;
                    float v  = acc[i][jj][r]     + bias[cm];
                    float vp = acc[i][jj ^ 2][r] + bias[cm ^ 32];
                    float2 cs = (jj & 1) ? cs1 : cs0;
                    float res = (d < 32) ? (v * cs.x - vp * cs.y)
                                         : (v * cs.x + vp * cs.y);
                    outb[(((size_t)(b_ * NHEAD + h) * S_LEN + s) << 6) + d] = f2b(res * osc);
                }
            }
        }
    }
}

// ---------------- O-proj GEMM: BM=64 x BN=128, 2-phase double-buffered ---------
__global__ __launch_bounds__(256) void gemm_o(
    const short* __restrict__ A, const short* __restrict__ Bw,
    const float* __restrict__ bias, float* __restrict__ outf)
{
    __shared__ short Asl[2][64 * 32];
    __shared__ short Bsl[2][128 * 32];
    const int t = threadIdx.x;
    const int lane = t & 63;
    const int l15 = lane & 15, l4 = lane >> 4;
    const int wid = t >> 6;
    const int blk = blockIdx.x;                 // 512
    const int tn = (blk & 7) * 128;             // xcd x owns n-tile x
    const int tm = (blk >> 3) * 64;
    const int K = 1024, N = 1024;
    const int wrow = (wid >> 1) * 32, wcol = (wid & 1) * 64;

    f4v acc[2][4];
#pragma unroll
    for (int i = 0; i < 2; ++i)
#pragma unroll
        for (int jj = 0; jj < 4; ++jj) acc[i][jj] = (f4v){0.f, 0.f, 0.f, 0.f};

    const int r0 = t >> 2;
    const int c0 = (t & 3) * 8;
    const int wbase = (t & ~63) * 8;

#define OSTAGE(buf, kt) do { const int k0_ = (kt) << 5;                            \
        gload_lds16(A  + (size_t)(tm + r0)      * K + k0_ + c0, &Asl[buf][wbase]);        \
        gload_lds16(Bw + (size_t)(tn + r0)      * K + k0_ + c0, &Bsl[buf][wbase]);        \
        gload_lds16(Bw + (size_t)(tn + 64 + r0) * K + k0_ + c0, &Bsl[buf][2048 + wbase]); \
    } while (0)

    OSTAGE(0, 0);
    __syncthreads();
    int cur = 0;
    for (int kt = 0; kt < 32; ++kt) {
        if (kt < 31) OSTAGE(cur ^ 1, kt + 1);
        s8v af[2], bf[4];
#pragma unroll
        for (int i = 0; i < 2; ++i)
            af[i] = *(const s8v*)&Asl[cur][(wrow + i * 16 + l15) * 32 + 8 * l4];
#pragma unroll
        for (int jj = 0; jj < 4; ++jj)
            bf[jj] = *(const s8v*)&Bsl[cur][(wcol + jj * 16 + l15) * 32 + 8 * l4];
#pragma unroll
        for (int i = 0; i < 2; ++i)
#pragma unroll
            for (int jj = 0; jj < 4; ++jj)
                acc[i][jj] = __builtin_amdgcn_mfma_f32_16x16x32_bf16(af[i], bf[jj], acc[i][jj], 0, 0, 0);
        __syncthreads();
        cur ^= 1;
    }
#undef OSTAGE

#pragma unroll
    for (int i = 0; i < 2; ++i) {
        int rowb = tm + wrow + i * 16 + l4 * 4;
#pragma unroll
        for (int jj = 0; jj < 4; ++jj) {
            int col = tn + wcol + jj * 16 + l15;
            float bv = bias[col];
#pragma unroll
            for (int r = 0; r < 4; ++r)
                outf[(size_t)(rowb + r) * N + col] = acc[i][jj][r] + bv;
        }
    }
}

// ---------------- attention: 4 warps x 32 q-rows, swapped-operand 32x32 MFMA ---
// Q pre-scaled by 0.125*log2e; K [bh][s][64]; Vt [bh][d][s]. 512 blocks.
#define SWB(row, bofs) ((bofs) ^ (((row) & 7) << 4))

__global__ __launch_bounds__(256) void attn2_kernel(
    const short* __restrict__ Q, const short* __restrict__ K,
    const short* __restrict__ Vt, short* __restrict__ O)
{
    __shared__ short Kl[2][4096];   // [key][d] 64x64, swizzled (8KB/buf)
    __shared__ short Vl[2][4096];   // [d][key] 64x64, swizzled

    const int t = threadIdx.x, lane = t & 63, wid = t >> 6;
    const int q5 = lane & 31, hi = lane >> 5;

    // XCD decode: 512 blocks; xcd x owns bh [4x,4x+4) over all 16 q-blocks
    const int blk = blockIdx.x;
    const int x = blk & 7, j = blk >> 3;       // j in [0,64)
    const int bh = x * 4 + (j & 3), qb = j >> 2;

    const short* Qb = Q + (size_t)bh * S_LEN * 64;
    const char*  Kb = (const char*)(K  + (size_t)bh * S_LEN * 64);
    const char*  Vb = (const char*)(Vt + (size_t)bh * S_LEN * 64);
    const int qrow = qb * 128 + wid * 32 + q5;

    s8v qf[4];
#pragma unroll
    for (int sl = 0; sl < 4; ++sl)
        qf[sl] = *(const s8v*)&Qb[(size_t)qrow * 64 + sl * 16 + hi * 8];

    f16v oacc[2];
#pragma unroll
    for (int dt = 0; dt < 2; ++dt)
#pragma unroll
        for (int e = 0; e < 16; ++e) oacc[dt][e] = 0.f;
    float m2 = -1e30f, lsum = 0.f;

    const int skey  = t >> 3;                  // 0..31
    const int sboff = (t & 7) * 16;
    const int ssw   = SWB(skey, sboff);        // (row&7) invariant under +32
    const size_t koffB = (size_t)skey * 128  + ssw;
    const size_t voffB = (size_t)skey * 4096 + ssw;

#define STAGE(buf, kb) do {                                                        \
        gload_lds16(Kb + (size_t)(kb) * 128 + koffB,              &Kl[buf][wid * 512]);        \
        gload_lds16(Kb + (size_t)(kb) * 128 + koffB + 32 * 128,   &Kl[buf][2048 + wid * 512]); \
        gload_lds16(Vb + (size_t)(kb) * 2   + voffB,              &Vl[buf][wid * 512]);        \
        gload_lds16(Vb + (size_t)(kb) * 2   + voffB + 32 * 4096,  &Vl[buf][2048 + wid * 512]); \
    } while (0)

    STAGE(0, 0);
    __syncthreads();

    int cur = 0;
    for (int kt = 0; kt < S_LEN / 64; ++kt) {
        if (kt < S_LEN / 64 - 1) STAGE(cur ^ 1, (kt + 1) * 64);

        // ---- QK^T (swapped): lane q = l&31; 2 chunks of 32 keys ----
        f16v sc[2];
#pragma unroll
        for (int c = 0; c < 2; ++c) {
#pragma unroll
            for (int e = 0; e < 16; ++e) sc[c][e] = 0.f;
            const int krow = c * 32 + q5;
            const char* kbase = (const char*)&Kl[cur][0] + krow * 128;
            __builtin_amdgcn_s_setprio(1);
#pragma unroll
            for (int sl = 0; sl < 4; ++sl) {
                s8v kf = *(const s8v*)(kbase + SWB(krow, sl * 32 + hi * 16));
                sc[c] = __builtin_amdgcn_mfma_f32_32x32x16_bf16(kf, qf[sl], sc[c], 0, 0, 0);
            }
            __builtin_amdgcn_s_setprio(0);
        }

        // ---- online softmax (log2 domain) ----
        float pm = -1e30f;
#pragma unroll
        for (int c = 0; c < 2; ++c)
#pragma unroll
            for (int e = 0; e < 16; e += 2)
                pm = fmaxf(pm, fmaxf(sc[c][e], sc[c][e + 1]));
        pm = fmaxf(pm, __shfl_xor(pm, 32, 64));
        if (__any(pm > m2 + 8.0f)) {          // defer-max (T13)
            float m2n = fmaxf(m2, pm);
            float fr = __builtin_amdgcn_exp2f(m2 - m2n);
            lsum *= fr;
#pragma unroll
            for (int dt = 0; dt < 2; ++dt)
#pragma unroll
                for (int e = 0; e < 16; ++e) oacc[dt][e] *= fr;
            m2 = m2n;
        }
        float ps = 0.f;
#pragma unroll
        for (int c = 0; c < 2; ++c)
#pragma unroll
            for (int e = 0; e < 16; ++e) {
                float p = __builtin_amdgcn_exp2f(sc[c][e] - m2);
                sc[c][e] = p;
                ps += p;
            }
        lsum += ps;

        // ---- P->bf16 frags (cvt_pk + permlane32_swap) and PV (swapped) ----
#pragma unroll
        for (int c = 0; c < 2; ++c) {
#pragma unroll
            for (int ks = 0; ks < 2; ++ks) {
                const int b0 = ks * 8;
                unsigned x0 = cvtpk(sc[c][b0 + 0], sc[c][b0 + 1]);
                unsigned y0 = cvtpk(sc[c][b0 + 4], sc[c][b0 + 5]);
                unsigned x1 = cvtpk(sc[c][b0 + 2], sc[c][b0 + 3]);
                unsigned y1 = cvtpk(sc[c][b0 + 6], sc[c][b0 + 7]);
                plswap(x0, y0);
                plswap(x1, y1);
                union { unsigned u[4]; s8v s; } pf;
                pf.u[0] = x0; pf.u[1] = x1; pf.u[2] = y0; pf.u[3] = y1;
                __builtin_amdgcn_s_setprio(1);
#pragma unroll
                for (int dt = 0; dt < 2; ++dt) {
                    const int vrow = dt * 32 + q5;
                    s8v vf = *(const s8v*)((const char*)&Vl[cur][0] + vrow * 128 +
                                           SWB(vrow, c * 64 + ks * 32 + hi * 16));
                    oacc[dt] = __builtin_amdgcn_mfma_f32_32x32x16_bf16(vf, pf.s, oacc[dt], 0, 0, 0);
                }
                __builtin_amdgcn_s_setprio(0);
            }
        }

        __syncthreads();
        cur ^= 1;
    }

    // ---- epilogue ----
    float ls = lsum + __shfl_xor(lsum, 32, 64);
    float inv = 1.0f / ls;
    const int b_ = bh >> 4, h = bh & 15;
    const size_t rbase = ((size_t)(b_ * S_LEN + qrow)) * HID_ + h * 64;
#pragma unroll
    for (int dt = 0; dt < 2; ++dt)
#pragma unroll
        for (int g = 0; g < 4; ++g) {
            s4v o4;
#pragma unroll
            for (int jj = 0; jj < 4; ++jj) o4[jj] = f2b(oacc[dt][g * 4 + jj] * inv);
            const int d0 = dt * 32 + g * 8 + hi * 4;
            *(s4v*)&O[rbase + d0] = o4;
        }
}

// ---------------- launch ----------------
extern "C" void kernel_launch(void* const* d_in, const int* in_sizes, int n_in,
                              void* d_out, int out_size, void* d_ws, size_t ws_size,
                              hipStream_t stream)
{
    const float* X  = (const float*)d_in[0];
    const float* Wq = (const float*)d_in[1];
    const float* bq = (const float*)d_in[2];
    const float* Wk = (const float*)d_in[3];
    const float* bk = (const float*)d_in[4];
    const float* Wv = (const float*)d_in[5];
    const float* bv = (const float*)d_in[6];
    const float* Wo = (const float*)d_in[7];
    const float* bo = (const float*)d_in[8];
    float* out = (float*)d_out;

    char* ws = (char*)d_ws;
    short*  Xb   = (short*) (ws);                      // 8 MB  [4096][1024] bf16
    short*  Wcat = (short*) (ws + ( 8u << 20));        // 6 MB  Wq|Wk|Wv bf16
    short*  Wob  = (short*) (ws + (14u << 20));        // 2 MB
    float2* rtab = (float2*)(ws + (16u << 20));        // 512 KB [2048][32]
    short*  Qbh  = (short*) (ws + (17u << 20));        // 8 MB  [32][2048][64]
    short*  Kbh  = (short*) (ws + (25u << 20));
    short*  Vbh  = (short*) (ws + (33u << 20));        // 8 MB  [32][64][2048] (V^T)
    short*  Obf  = (short*) (ws + (41u << 20));        // 8 MB  [4096][1024]

    f2b_kernel<<<4096, 256, 0, stream>>>(X, Xb, 1048576);
    f2bw_kernel<<<dim3(1024, 4), 256, 0, stream>>>(Wq, Wk, Wv, Wo, Wcat, Wob);
    rope_table_kernel<<<256, 256, 0, stream>>>(rtab);

    gemm_qkv<<<768, 256, 0, stream>>>(Xb, Wcat, bq, bk, bv, Qbh, Kbh, Vbh, rtab);
    attn2_kernel<<<512, 256, 0, stream>>>(Qbh, Kbh, Vbh, Obf);
    gemm_o<<<512, 256, 0, stream>>>(Obf, Wob, bo, out);
}